// Round 2
// baseline (2459.241 us; speedup 1.0000x reference)
//
#include <hip/hip_runtime.h>
#include <hip/hip_bf16.h>

typedef __attribute__((ext_vector_type(4))) float f32x4;
typedef __attribute__((ext_vector_type(8))) short short8;
typedef __attribute__((ext_vector_type(8))) unsigned short ushort8;

#define T_STEPS 512
#define BATCH   128
#define IDIM    512
#define HDIM    1024
#define KTOT    1536           // IDIM + HDIM (fused [x_t | h] @ [Wx; Wh])
#define NGROUP  8              // batch groups (16 rows each)
#define GROWS   16             // batch rows per group
#define NCB     16             // column-blocks per group
#define CBW     64             // output columns per block (4 waves x 16)
#define HBUF_ELEMS (BATCH * HDIM)
#define XBUFB   (GROWS * IDIM * 2)   // bytes per xs half
#define NFLAG   (NGROUP * 64)        // per-WAVE flags, packed 4B (coalesced polls)

// f32 -> bf16 round-to-nearest-even
__device__ __forceinline__ unsigned short f2bf(float f) {
    unsigned int u = __builtin_bit_cast(unsigned int, f);
    u = (u + 0x7FFFu + ((u >> 16) & 1u)) >> 16;
    return (unsigned short)u;
}

// fast tanh: clamp +-9, e2x = exp2(2*log2e*x), (e2x-1)*rcp(e2x+1).
__device__ __forceinline__ float fast_tanh(float x) {
    x = fminf(9.0f, fmaxf(-9.0f, x));
    float t = __builtin_exp2f(x * 2.8853900817779268f);
    return (t - 1.0f) * __builtin_amdgcn_rcpf(t + 1.0f);
}

// XOR swizzles (row strides 0 mod 128B; XOR row low-bits into the 16B-slot index)
__device__ __forceinline__ int swzX(int row, int c) { return row * 1024 + (c ^ ((row & 7) << 4)); }
__device__ __forceinline__ int swzH(int row, int c) { return row * 2048 + (c ^ ((row & 7) << 4)); }

// ---- coherence scopes ------------------------------------------------------
// gfx950 {sc1,sc0} is a 2-bit SCOPE field: 00=CU, 01=SE, 10=DEVICE, 11=SYSTEM.
// (Round-1 lesson: sc0-only is ≤CU scope — polling with it deadlocks on stale
//  L1. NOT an L1-bypass bit.)
// FLAGS stay at system scope (sc0 sc1) — the proven-safe poll/publish path.
// H DATA moves to device scope (sc1-only): cross-XCD coherent (same scope HIP
// device atomics use), but point-of-coherence is the LLC instead of HBM —
// round-0 counters showed WRITE_SIZE==h-store bytes, i.e. system-scope stores
// were paying an HBM write-through + ack every step.
__device__ __forceinline__ void st_u32_sys(unsigned int* p, unsigned int v) {
    asm volatile("global_store_dword %0, %1, off sc0 sc1" :: "v"(p), "v"(v) : "memory");
}
// h-value store, device scope
__device__ __forceinline__ void st_h16_dev(unsigned short* p, unsigned short v) {
    asm volatile("global_store_short %0, %1, off sc1" :: "v"(p), "v"(v) : "memory");
}
// issue 8 pipelined dwordx4 h-tile loads (128 B), device scope, NO wait
// (drained by counted vmcnt)
__device__ __forceinline__ void ldh_issue_dev(const unsigned short* p, ushort8 v[8]) {
    asm volatile(
        "global_load_dwordx4 %0, %8, off sc1\n\t"
        "global_load_dwordx4 %1, %8, off offset:16 sc1\n\t"
        "global_load_dwordx4 %2, %8, off offset:32 sc1\n\t"
        "global_load_dwordx4 %3, %8, off offset:48 sc1\n\t"
        "global_load_dwordx4 %4, %8, off offset:64 sc1\n\t"
        "global_load_dwordx4 %5, %8, off offset:80 sc1\n\t"
        "global_load_dwordx4 %6, %8, off offset:96 sc1\n\t"
        "global_load_dwordx4 %7, %8, off offset:112 sc1"
        : "=&v"(v[0]), "=&v"(v[1]), "=&v"(v[2]), "=&v"(v[3]),
          "=&v"(v[4]), "=&v"(v[5]), "=&v"(v[6]), "=&v"(v[7])
        : "v"(p) : "memory");
}
// issue 8 pipelined dwordx4 x-tile loads (128 B of f32), normal caching, NO wait
__device__ __forceinline__ void ldx_issue(const float* p, float4 v[8]) {
    asm volatile(
        "global_load_dwordx4 %0, %8, off\n\t"
        "global_load_dwordx4 %1, %8, off offset:16\n\t"
        "global_load_dwordx4 %2, %8, off offset:32\n\t"
        "global_load_dwordx4 %3, %8, off offset:48\n\t"
        "global_load_dwordx4 %4, %8, off offset:64\n\t"
        "global_load_dwordx4 %5, %8, off offset:80\n\t"
        "global_load_dwordx4 %6, %8, off offset:96\n\t"
        "global_load_dwordx4 %7, %8, off offset:112"
        : "=&v"(v[0]), "=&v"(v[1]), "=&v"(v[2]), "=&v"(v[3]),
          "=&v"(v[4]), "=&v"(v[5]), "=&v"(v[6]), "=&v"(v[7])
        : "v"(p) : "memory");
}

// ---------------------------------------------------------------------------
// Prep: WT[n][k] = bf16(W[k][n]) for W in {Wx (koff=0), Wh (koff=IDIM)}.
__global__ void prep_transpose(const float* __restrict__ src,
                               unsigned short* __restrict__ dst, int koff) {
    __shared__ float tl[32][33];
    const int tx = threadIdx.x, ty = threadIdx.y;
    const int k0 = blockIdx.x * 32, n0 = blockIdx.y * 32;
#pragma unroll
    for (int q = 0; q < 4; ++q) {
        int kk = ty * 4 + q;
        tl[kk][tx] = src[(size_t)(k0 + kk) * HDIM + n0 + tx];
    }
    __syncthreads();
#pragma unroll
    for (int q = 0; q < 4; ++q) {
        int nn = ty * 4 + q;
        dst[(size_t)(n0 + nn) * KTOT + koff + k0 + tx] = f2bf(tl[tx][nn]);
    }
}

// Prep: hbuf slot0=bf16(h0); bsum=bx+bh; flags=0. Runs every launch (graph
// replay determinism); dispatch-end release flushes these for rnn_fused.
__global__ void prep_misc(const float* __restrict__ h0, const float* __restrict__ bx,
                          const float* __restrict__ bh, float* __restrict__ bsum,
                          unsigned short* __restrict__ hbuf, unsigned int* __restrict__ flags) {
    int idx = blockIdx.x * 256 + threadIdx.x;
    if (idx < HBUF_ELEMS) {
        hbuf[idx] = f2bf(h0[idx]);
    } else if (idx < HBUF_ELEMS + HDIM) {
        int j = idx - HBUF_ELEMS;
        bsum[j] = bx[j] + bh[j];
    } else if (idx < HBUF_ELEMS + HDIM + NFLAG) {
        flags[idx - HBUF_ELEMS - HDIM] = 0;
    }
}

__global__ void ws_fail_kernel(float* out) { out[0] = 1.0e6f; }  // ws_size diagnostic

// ---------------------------------------------------------------------------
// Fused recurrence. Grid = 128 blocks: group g = blockIdx%8 (16 batch rows),
// col-block cb = blockIdx/8 (64 cols). W column-slice pinned in registers.
// Iteration order: A0 double-pumped per-wave quartet poll -> A h+x load issue
// -> B x-MFMA under load latency -> C counted vmcnt(8) (poll leftover + h
// retired; x keeps flying) -> D h-MFMA -> E fast-tanh + h stores (device
// scope) -> F vmcnt(0) drain + per-wave flag publish (system scope) -> G
// x-stage -> loop-end barrier. All asm load values live within ONE iteration.
__global__ __launch_bounds__(256, 1) void rnn_fused(
        const float* __restrict__ x, const unsigned short* __restrict__ WT,
        const float* __restrict__ bsum, unsigned short* __restrict__ hbuf,
        unsigned int* __restrict__ flags, float* __restrict__ out) {
    __shared__ unsigned short xs[2 * GROWS * IDIM];   // 32 KB (double-buffered x tile)
    __shared__ unsigned short hs[GROWS * HDIM];       // 32 KB (h tile)
    char* xb = (char*)xs;
    char* hb = (char*)hs;
    const int tid  = threadIdx.x;
    const int bid  = blockIdx.x;
    const int g    = bid & 7;
    const int cb   = bid >> 3;
    const int lane = tid & 63;
    const int wid  = tid >> 6;
    const int lrow = lane & 15;    // A row / C col low bits
    const int kg   = lane >> 4;    // k-group 0..3
    const int ncol = cb * CBW + wid * 16 + lrow;

    // Resident B fragments: lane holds WT[ncol][kc*32 + kg*8 .. +7]
    short8 Bf[48];
    {
        const short8* wp = (const short8*)(WT + (size_t)ncol * KTOT);
#pragma unroll
        for (int kc = 0; kc < 48; ++kc) Bf[kc] = wp[kc * 4 + kg];
    }
#pragma unroll
    for (int kc = 0; kc < 48; ++kc) asm volatile("" : "+v"(Bf[kc]));
    const float bias = bsum[ncol];

    const int sm  = tid & 15;      // staged row 0..15
    const int seg = tid >> 4;      // 1/16 of the row
    unsigned int* const myflag = &flags[(g << 6) + (cb << 2) + wid];
    // wave w's staged columns come from producer blocks 4w..4w+3 only:
    // lane checks flag of producer block (wid*4 + lane>>4), wave sub-flag lane&3
    const unsigned int* const pollp =
        &flags[(g << 6) + (((wid << 2) + (lane >> 4)) << 2) + (lane & 3)];
    const size_t rowoff = (size_t)(g * GROWS + sm) * HDIM + seg * 64;

    // ---- prologue: stage x(0) into xs buf 0 (deterministic queue: drain) ----
    {
        float4 xv0[8];
        ldx_issue(x + ((size_t)g * GROWS + sm) * IDIM + seg * 32, xv0);
        asm volatile("s_waitcnt vmcnt(0)" ::: "memory");
        __builtin_amdgcn_sched_barrier(0);
#pragma unroll
        for (int q = 0; q < 4; ++q) {
            float4 a = xv0[2 * q], b = xv0[2 * q + 1];
            ushort8 w;
            w[0] = f2bf(a.x); w[1] = f2bf(a.y); w[2] = f2bf(a.z); w[3] = f2bf(a.w);
            w[4] = f2bf(b.x); w[5] = f2bf(b.y); w[6] = f2bf(b.z); w[7] = f2bf(b.w);
            *(ushort8*)(xb + swzX(sm, seg * 64 + q * 16)) = w;
        }
        asm volatile("s_waitcnt lgkmcnt(0)" ::: "memory");
        __builtin_amdgcn_s_barrier();
        __builtin_amdgcn_sched_barrier(0);
    }

    for (int t = 0; t < T_STEPS; ++t) {
        const bool has_next = (t + 1 < T_STEPS);

        // ---- A0: double-pumped quartet poll (system scope, proven safe).
        // Two flag loads in flight; vmcnt(1) ping-pong halves detection
        // quantization. Exits with EXACTLY ONE poll load still outstanding —
        // it is OLDER than the h-loads, so C's vmcnt(8) waits poll+8h retired
        // (what we need) and F's vmcnt(0) drains it. sched_barrier(0) after
        // each wait pins the v_cmp use after the waitcnt (rule #18).
        {
            const unsigned int tgt = (unsigned int)t;
            unsigned int v0, v1;
            asm volatile("global_load_dword %0, %1, off sc0 sc1"
                         : "=v"(v0) : "v"(pollp) : "memory");
            while (true) {
                asm volatile("global_load_dword %0, %1, off sc0 sc1"
                             : "=v"(v1) : "v"(pollp) : "memory");
                asm volatile("s_waitcnt vmcnt(1)" ::: "memory");
                __builtin_amdgcn_sched_barrier(0);
                if (__all(v0 >= tgt)) break;
                asm volatile("global_load_dword %0, %1, off sc0 sc1"
                             : "=v"(v0) : "v"(pollp) : "memory");
                asm volatile("s_waitcnt vmcnt(1)" ::: "memory");
                __builtin_amdgcn_sched_barrier(0);
                if (__all(v1 >= tgt)) break;
            }
        }

        // ---- A: issue h(t) loads FIRST (oldest after poll), then x(t+1) ----
        ushort8 hv[8];
        ldh_issue_dev(hbuf + (size_t)(t & 1) * HBUF_ELEMS + rowoff, hv);
        float4 xv[8];
        if (has_next)
            ldx_issue(x + ((size_t)(t + 1) * BATCH + g * GROWS + sm) * IDIM + seg * 32, xv);

        // ---- B: x-side MFMA (kc 0..15) under the h/x load latency ----
        const char* xcur = xb + (t & 1) * XBUFB;
        f32x4 acc0 = {0.f, 0.f, 0.f, 0.f}, acc1 = acc0, acc2 = acc0, acc3 = acc0;
#pragma unroll
        for (int kk = 0; kk < 4; ++kk) {
            short8 a0 = *(const short8*)(xcur + swzX(lrow, (4 * kk + 0) * 64 + kg * 16));
            short8 a1 = *(const short8*)(xcur + swzX(lrow, (4 * kk + 1) * 64 + kg * 16));
            short8 a2 = *(const short8*)(xcur + swzX(lrow, (4 * kk + 2) * 64 + kg * 16));
            short8 a3 = *(const short8*)(xcur + swzX(lrow, (4 * kk + 3) * 64 + kg * 16));
            acc0 = __builtin_amdgcn_mfma_f32_16x16x32_bf16(a0, Bf[4 * kk + 0], acc0, 0, 0, 0);
            acc1 = __builtin_amdgcn_mfma_f32_16x16x32_bf16(a1, Bf[4 * kk + 1], acc1, 0, 0, 0);
            acc2 = __builtin_amdgcn_mfma_f32_16x16x32_bf16(a2, Bf[4 * kk + 2], acc2, 0, 0, 0);
            acc3 = __builtin_amdgcn_mfma_f32_16x16x32_bf16(a3, Bf[4 * kk + 3], acc3, 0, 0, 0);
        }

        // ---- C: counted wait = poll leftover + h loads done, x keeps flying ----
        if (has_next) asm volatile("s_waitcnt vmcnt(8)" ::: "memory");
        else          asm volatile("s_waitcnt vmcnt(0)" ::: "memory");
        __builtin_amdgcn_sched_barrier(0);
#pragma unroll
        for (int q = 0; q < 8; ++q)
            *(ushort8*)(hb + swzH(sm, seg * 128 + q * 16)) = hv[q];
        asm volatile("s_waitcnt lgkmcnt(0)" ::: "memory");
        __builtin_amdgcn_s_barrier();          // raw: no auto vmcnt(0) drain
        __builtin_amdgcn_sched_barrier(0);

        // ---- D: h-side MFMA (kc 16..47) ----
#pragma unroll
        for (int kk = 4; kk < 12; ++kk) {
            short8 a0 = *(const short8*)(hb + swzH(lrow, (4 * kk - 16 + 0) * 64 + kg * 16));
            short8 a1 = *(const short8*)(hb + swzH(lrow, (4 * kk - 16 + 1) * 64 + kg * 16));
            short8 a2 = *(const short8*)(hb + swzH(lrow, (4 * kk - 16 + 2) * 64 + kg * 16));
            short8 a3 = *(const short8*)(hb + swzH(lrow, (4 * kk - 16 + 3) * 64 + kg * 16));
            acc0 = __builtin_amdgcn_mfma_f32_16x16x32_bf16(a0, Bf[4 * kk + 0], acc0, 0, 0, 0);
            acc1 = __builtin_amdgcn_mfma_f32_16x16x32_bf16(a1, Bf[4 * kk + 1], acc1, 0, 0, 0);
            acc2 = __builtin_amdgcn_mfma_f32_16x16x32_bf16(a2, Bf[4 * kk + 2], acc2, 0, 0, 0);
            acc3 = __builtin_amdgcn_mfma_f32_16x16x32_bf16(a3, Bf[4 * kk + 3], acc3, 0, 0, 0);
        }

        // ---- E: epilogue. C row = kg*4 + r, col = ncol ----
        if (!has_next) {
#pragma unroll
            for (int r = 0; r < 4; ++r) {
                float pre = acc0[r] + acc1[r] + acc2[r] + acc3[r] + bias;
                out[(size_t)(g * GROWS + kg * 4 + r) * HDIM + ncol] = fast_tanh(pre);
            }
            break;
        }
        {
            unsigned short* hdst = hbuf + (size_t)((t + 1) & 1) * HBUF_ELEMS;
#pragma unroll
            for (int r = 0; r < 4; ++r) {
                float pre = acc0[r] + acc1[r] + acc2[r] + acc3[r] + bias;
                float hvf = fast_tanh(pre);
                st_h16_dev(hdst + (size_t)(g * GROWS + kg * 4 + r) * HDIM + ncol, f2bf(hvf));
            }
        }

        // ---- F: drain stores (+x loads + poll leftover) then publish ----
        // Device-scope store-ack stops at the LLC (vs HBM for sc0 sc1):
        // the vmcnt(0) here is the chain's biggest RT — this is the cut.
        asm volatile("s_waitcnt vmcnt(0)" ::: "memory");
        __builtin_amdgcn_sched_barrier(0);
        if (lane == 0) st_u32_sys(myflag, (unsigned int)(t + 1));

        // ---- G: stage x(t+1) regs -> xs[(t+1)&1] (no waits) ----
        {
            char* xnxt = xb + ((t + 1) & 1) * XBUFB;
#pragma unroll
            for (int q = 0; q < 4; ++q) {
                float4 a = xv[2 * q], b = xv[2 * q + 1];
                ushort8 w;
                w[0] = f2bf(a.x); w[1] = f2bf(a.y); w[2] = f2bf(a.z); w[3] = f2bf(a.w);
                w[4] = f2bf(b.x); w[5] = f2bf(b.y); w[6] = f2bf(b.z); w[7] = f2bf(b.w);
                *(ushort8*)(xnxt + swzX(sm, seg * 64 + q * 16)) = w;
            }
        }

        // ---- loop end: hs/xs reuse guard — all local waves past D-reads and
        // published (F) before anyone stages step t+1 (raw barrier, LDS wait) ----
        asm volatile("s_waitcnt lgkmcnt(0)" ::: "memory");
        __builtin_amdgcn_s_barrier();
        __builtin_amdgcn_sched_barrier(0);
    }
}

// ---------------------------------------------------------------------------
extern "C" void kernel_launch(void* const* d_in, const int* in_sizes, int n_in,
                              void* d_out, int out_size, void* d_ws, size_t ws_size,
                              hipStream_t stream) {
    const float* x  = (const float*)d_in[0];
    const float* h0 = (const float*)d_in[1];
    const float* Wx = (const float*)d_in[2];
    const float* bx = (const float*)d_in[3];
    const float* Wh = (const float*)d_in[4];
    const float* bh = (const float*)d_in[5];
    float* out = (float*)d_out;

    // workspace layout (128B-aligned pieces)
    const size_t OFF_WT = 0;                    // 1024*1536 bf16 = 3,145,728 B
    const size_t OFF_BS = 3145728;              // 1024 f32 = 4096 B
    const size_t OFF_HB = 3149824;              // 2*128*1024 bf16 = 524,288 B
    const size_t OFF_FL = 3674112;              // 512 u32 packed flags = 2048 B
    const size_t WS_NEED = 3676160;
    if (ws_size < WS_NEED) {                    // diagnostic: absmax ~1e6 => ws too small
        hipLaunchKernelGGL(ws_fail_kernel, dim3(1), dim3(1), 0, stream, out);
        return;
    }

    unsigned short* WT    = (unsigned short*)((char*)d_ws + OFF_WT);
    float*          bsum  = (float*)((char*)d_ws + OFF_BS);
    unsigned short* hbuf  = (unsigned short*)((char*)d_ws + OFF_HB);
    unsigned int*   flags = (unsigned int*)((char*)d_ws + OFF_FL);

    prep_transpose<<<dim3(IDIM / 32, HDIM / 32), dim3(32, 8), 0, stream>>>(Wx, WT, 0);
    prep_transpose<<<dim3(HDIM / 32, HDIM / 32), dim3(32, 8), 0, stream>>>(Wh, WT, IDIM);
    const int misc_total = HBUF_ELEMS + HDIM + NFLAG;
    prep_misc<<<dim3((misc_total + 255) / 256), dim3(256), 0, stream>>>(
        h0, bx, bh, bsum, hbuf, flags);
    rnn_fused<<<dim3(NGROUP * NCB), dim3(256), 0, stream>>>(
        x, WT, bsum, hbuf, flags, out);
}

// Round 3
// 2399.932 us; speedup vs baseline: 1.0247x; 1.0247x over previous
//
#include <hip/hip_runtime.h>
#include <hip/hip_bf16.h>

typedef __attribute__((ext_vector_type(4))) float f32x4;
typedef __attribute__((ext_vector_type(8))) short short8;
typedef __attribute__((ext_vector_type(8))) unsigned short ushort8;

#define T_STEPS 512
#define BATCH   128
#define IDIM    512
#define HDIM    1024
#define KTOT    1536           // IDIM + HDIM (fused [x_t | h] @ [Wx; Wh])
#define NGROUP  8              // batch groups (16 rows each)
#define GROWS   16             // batch rows per group
#define NCB     16             // column-blocks per group
#define CBW     64             // output columns per block (4 waves x 16)
#define HBUF_ELEMS (BATCH * HDIM)
#define XBUFB   (GROWS * IDIM * 2)   // bytes per xs half
#define NFLAG   (NGROUP * 64)        // per-WAVE flags, packed 4B (coalesced polls)

// f32 -> bf16 round-to-nearest-even
__device__ __forceinline__ unsigned short f2bf(float f) {
    unsigned int u = __builtin_bit_cast(unsigned int, f);
    u = (u + 0x7FFFu + ((u >> 16) & 1u)) >> 16;
    return (unsigned short)u;
}

// fast tanh: clamp +-9, e2x = exp2(2*log2e*x), (e2x-1)*rcp(e2x+1).
__device__ __forceinline__ float fast_tanh(float x) {
    x = fminf(9.0f, fmaxf(-9.0f, x));
    float t = __builtin_exp2f(x * 2.8853900817779268f);
    return (t - 1.0f) * __builtin_amdgcn_rcpf(t + 1.0f);
}

// XOR swizzles (row strides 0 mod 128B; XOR row low-bits into the 16B-slot index)
__device__ __forceinline__ int swzX(int row, int c) { return row * 1024 + (c ^ ((row & 7) << 4)); }
__device__ __forceinline__ int swzH(int row, int c) { return row * 2048 + (c ^ ((row & 7) << 4)); }

// ---- proven IF-coherent primitives (sc0 sc1): no fences, no L2 maintenance ----
// Coherence model (established rounds 0-2): group g's 16 blocks share an XCD;
// sc0 sc1 stores write-through and UPDATE the local L2, so consumer loads are
// L2-hits (FETCH shows no h re-fetch). The LLC absorbs the write-through
// (WRITE_SIZE == h bytes). Scope downgrades are either unsafe (sc0-only:
// round-1 deadlock) or a non-win (sc1-only: round-2).
__device__ __forceinline__ void st_u32_if(unsigned int* p, unsigned int v) {
    asm volatile("global_store_dword %0, %1, off sc0 sc1" :: "v"(p), "v"(v) : "memory");
}
// packed 4x bf16 (8B) h store — one transaction replaces four 2B stores
__device__ __forceinline__ void st_u64_if(unsigned short* p, unsigned int lo, unsigned int hi) {
    unsigned long long v = ((unsigned long long)hi << 32) | (unsigned long long)lo;
    asm volatile("global_store_dwordx2 %0, %1, off sc0 sc1" :: "v"(p), "v"(v) : "memory");
}
__device__ __forceinline__ unsigned int ld_u32_if(const unsigned int* p) {
    unsigned int v;
    asm volatile("global_load_dword %0, %1, off sc0 sc1\n\ts_waitcnt vmcnt(0)"
                 : "=v"(v) : "v"(p) : "memory");
    return v;
}
// issue 8 pipelined dwordx4 h-tile loads (128 B), NO wait (drained by counted vmcnt)
__device__ __forceinline__ void ldh_issue_if(const unsigned short* p, ushort8 v[8]) {
    asm volatile(
        "global_load_dwordx4 %0, %8, off sc0 sc1\n\t"
        "global_load_dwordx4 %1, %8, off offset:16 sc0 sc1\n\t"
        "global_load_dwordx4 %2, %8, off offset:32 sc0 sc1\n\t"
        "global_load_dwordx4 %3, %8, off offset:48 sc0 sc1\n\t"
        "global_load_dwordx4 %4, %8, off offset:64 sc0 sc1\n\t"
        "global_load_dwordx4 %5, %8, off offset:80 sc0 sc1\n\t"
        "global_load_dwordx4 %6, %8, off offset:96 sc0 sc1\n\t"
        "global_load_dwordx4 %7, %8, off offset:112 sc0 sc1"
        : "=&v"(v[0]), "=&v"(v[1]), "=&v"(v[2]), "=&v"(v[3]),
          "=&v"(v[4]), "=&v"(v[5]), "=&v"(v[6]), "=&v"(v[7])
        : "v"(p) : "memory");
}
// issue 8 pipelined dwordx4 x-tile loads (128 B of f32), normal caching, NO wait
__device__ __forceinline__ void ldx_issue(const float* p, float4 v[8]) {
    asm volatile(
        "global_load_dwordx4 %0, %8, off\n\t"
        "global_load_dwordx4 %1, %8, off offset:16\n\t"
        "global_load_dwordx4 %2, %8, off offset:32\n\t"
        "global_load_dwordx4 %3, %8, off offset:48\n\t"
        "global_load_dwordx4 %4, %8, off offset:64\n\t"
        "global_load_dwordx4 %5, %8, off offset:80\n\t"
        "global_load_dwordx4 %6, %8, off offset:96\n\t"
        "global_load_dwordx4 %7, %8, off offset:112"
        : "=&v"(v[0]), "=&v"(v[1]), "=&v"(v[2]), "=&v"(v[3]),
          "=&v"(v[4]), "=&v"(v[5]), "=&v"(v[6]), "=&v"(v[7])
        : "v"(p) : "memory");
}

// ---------------------------------------------------------------------------
// Prep: WT[n][k] = bf16(W[k][n]) for W in {Wx (koff=0), Wh (koff=IDIM)}.
__global__ void prep_transpose(const float* __restrict__ src,
                               unsigned short* __restrict__ dst, int koff) {
    __shared__ float tl[32][33];
    const int tx = threadIdx.x, ty = threadIdx.y;
    const int k0 = blockIdx.x * 32, n0 = blockIdx.y * 32;
#pragma unroll
    for (int q = 0; q < 4; ++q) {
        int kk = ty * 4 + q;
        tl[kk][tx] = src[(size_t)(k0 + kk) * HDIM + n0 + tx];
    }
    __syncthreads();
#pragma unroll
    for (int q = 0; q < 4; ++q) {
        int nn = ty * 4 + q;
        dst[(size_t)(n0 + nn) * KTOT + koff + k0 + tx] = f2bf(tl[tx][nn]);
    }
}

// Prep: hbuf slot0=bf16(h0); bsum=bx+bh; flags=0. Runs every launch (graph
// replay determinism); dispatch-end release flushes these for rnn_fused.
__global__ void prep_misc(const float* __restrict__ h0, const float* __restrict__ bx,
                          const float* __restrict__ bh, float* __restrict__ bsum,
                          unsigned short* __restrict__ hbuf, unsigned int* __restrict__ flags) {
    int idx = blockIdx.x * 256 + threadIdx.x;
    if (idx < HBUF_ELEMS) {
        hbuf[idx] = f2bf(h0[idx]);
    } else if (idx < HBUF_ELEMS + HDIM) {
        int j = idx - HBUF_ELEMS;
        bsum[j] = bx[j] + bh[j];
    } else if (idx < HBUF_ELEMS + HDIM + NFLAG) {
        flags[idx - HBUF_ELEMS - HDIM] = 0;
    }
}

__global__ void ws_fail_kernel(float* out) { out[0] = 1.0e6f; }  // ws_size diagnostic

// ---------------------------------------------------------------------------
// Fused recurrence. Grid = 128 blocks: group g = blockIdx%8 (16 batch rows),
// col-block cb = blockIdx/8 (64 cols). W column-slice pinned in registers.
// Round-3 changes vs the 2169µs baseline (protocol byte-identical):
//  * A0 poll: s_sleep(1) between failed checks — round 2 proved flag-line
//    traffic is a first-order cost (2x poll traffic => +13% time).
//  * MFMA operands SWAPPED (Bf as A, x/h frag as B): C is transposed, so a
//    lane holds one batch row x 4 CONSECUTIVE output cols. E becomes ONE
//    packed 8B store per thread (was 4 scattered 2B stores) => 4x fewer
//    store transactions under F's vmcnt(0); final out write is a float4.
__global__ __launch_bounds__(256, 1) void rnn_fused(
        const float* __restrict__ x, const unsigned short* __restrict__ WT,
        const float* __restrict__ bsum, unsigned short* __restrict__ hbuf,
        unsigned int* __restrict__ flags, float* __restrict__ out) {
    __shared__ unsigned short xs[2 * GROWS * IDIM];   // 32 KB (double-buffered x tile)
    __shared__ unsigned short hs[GROWS * HDIM];       // 32 KB (h tile)
    char* xb = (char*)xs;
    char* hb = (char*)hs;
    const int tid  = threadIdx.x;
    const int bid  = blockIdx.x;
    const int g    = bid & 7;
    const int cb   = bid >> 3;
    const int lane = tid & 63;
    const int wid  = tid >> 6;
    const int lrow = lane & 15;    // A-frag row / C^T col (batch row)
    const int kg   = lane >> 4;    // k-group 0..3
    const int ncol = cb * CBW + wid * 16 + lrow;          // WT row this lane carries
    const int n0   = cb * CBW + wid * 16 + kg * 4;        // C^T: this lane's 4 output cols

    // Resident W fragments: lane holds WT[ncol][kc*32 + kg*8 .. +7].
    // Used as the MFMA *A* operand (A[m=lane&15][k-chunk=lane>>4]) — the
    // lane layout is identical to the B-operand role it had before the swap.
    short8 Bf[48];
    {
        const short8* wp = (const short8*)(WT + (size_t)ncol * KTOT);
#pragma unroll
        for (int kc = 0; kc < 48; ++kc) Bf[kc] = wp[kc * 4 + kg];
    }
#pragma unroll
    for (int kc = 0; kc < 48; ++kc) asm volatile("" : "+v"(Bf[kc]));
    const float4 bias4 = *(const float4*)(bsum + n0);   // 4 consecutive col biases

    const int sm  = tid & 15;      // staged row 0..15
    const int seg = tid >> 4;      // 1/16 of the row
    unsigned int* const myflag = &flags[(g << 6) + (cb << 2) + wid];
    // wave w's staged columns come from producer blocks 4w..4w+3 only:
    // lane checks flag of producer block (wid*4 + lane>>4), wave sub-flag lane&3
    const unsigned int* const pollp =
        &flags[(g << 6) + (((wid << 2) + (lane >> 4)) << 2) + (lane & 3)];
    const size_t rowoff = (size_t)(g * GROWS + sm) * HDIM + seg * 64;

    // ---- prologue: stage x(0) into xs buf 0 (deterministic queue: drain) ----
    {
        float4 xv0[8];
        ldx_issue(x + ((size_t)g * GROWS + sm) * IDIM + seg * 32, xv0);
        asm volatile("s_waitcnt vmcnt(0)" ::: "memory");
        __builtin_amdgcn_sched_barrier(0);
#pragma unroll
        for (int q = 0; q < 4; ++q) {
            float4 a = xv0[2 * q], b = xv0[2 * q + 1];
            ushort8 w;
            w[0] = f2bf(a.x); w[1] = f2bf(a.y); w[2] = f2bf(a.z); w[3] = f2bf(a.w);
            w[4] = f2bf(b.x); w[5] = f2bf(b.y); w[6] = f2bf(b.z); w[7] = f2bf(b.w);
            *(ushort8*)(xb + swzX(sm, seg * 64 + q * 16)) = w;
        }
        asm volatile("s_waitcnt lgkmcnt(0)" ::: "memory");
        __builtin_amdgcn_s_barrier();
        __builtin_amdgcn_sched_barrier(0);
    }

    for (int t = 0; t < T_STEPS; ++t) {
        const bool has_next = (t + 1 < T_STEPS);

        // ---- A0: per-wave quartet poll, s_sleep-paced. First check is free
        // (steady state often satisfied); failed checks back off ~64cy to cut
        // flag-line L2 contention (round-2 lesson: poll traffic is expensive).
        {
            const unsigned int tgt = (unsigned int)t;
            unsigned int v = ld_u32_if(pollp);
            while (!__all(v >= tgt)) {
                __builtin_amdgcn_s_sleep(1);
                v = ld_u32_if(pollp);
            }
        }

        // ---- A: issue h(t) loads FIRST (oldest in queue), then x(t+1) ----
        ushort8 hv[8];
        ldh_issue_if(hbuf + (size_t)(t & 1) * HBUF_ELEMS + rowoff, hv);
        float4 xv[8];
        if (has_next)
            ldx_issue(x + ((size_t)(t + 1) * BATCH + g * GROWS + sm) * IDIM + seg * 32, xv);

        // ---- B: x-side MFMA (kc 0..15) under the h/x load latency.
        // Operands swapped: acc = C^T (lane: batch col lrow, rows kg*4+r = n).
        const char* xcur = xb + (t & 1) * XBUFB;
        f32x4 acc0 = {0.f, 0.f, 0.f, 0.f}, acc1 = acc0, acc2 = acc0, acc3 = acc0;
#pragma unroll
        for (int kk = 0; kk < 4; ++kk) {
            short8 a0 = *(const short8*)(xcur + swzX(lrow, (4 * kk + 0) * 64 + kg * 16));
            short8 a1 = *(const short8*)(xcur + swzX(lrow, (4 * kk + 1) * 64 + kg * 16));
            short8 a2 = *(const short8*)(xcur + swzX(lrow, (4 * kk + 2) * 64 + kg * 16));
            short8 a3 = *(const short8*)(xcur + swzX(lrow, (4 * kk + 3) * 64 + kg * 16));
            acc0 = __builtin_amdgcn_mfma_f32_16x16x32_bf16(Bf[4 * kk + 0], a0, acc0, 0, 0, 0);
            acc1 = __builtin_amdgcn_mfma_f32_16x16x32_bf16(Bf[4 * kk + 1], a1, acc1, 0, 0, 0);
            acc2 = __builtin_amdgcn_mfma_f32_16x16x32_bf16(Bf[4 * kk + 2], a2, acc2, 0, 0, 0);
            acc3 = __builtin_amdgcn_mfma_f32_16x16x32_bf16(Bf[4 * kk + 3], a3, acc3, 0, 0, 0);
        }

        // ---- C: counted wait = h loads done, x loads keep flying ----
        if (has_next) asm volatile("s_waitcnt vmcnt(8)" ::: "memory");
        else          asm volatile("s_waitcnt vmcnt(0)" ::: "memory");
        __builtin_amdgcn_sched_barrier(0);
#pragma unroll
        for (int q = 0; q < 8; ++q)
            *(ushort8*)(hb + swzH(sm, seg * 128 + q * 16)) = hv[q];
        asm volatile("s_waitcnt lgkmcnt(0)" ::: "memory");
        __builtin_amdgcn_s_barrier();          // raw: no auto vmcnt(0) drain
        __builtin_amdgcn_sched_barrier(0);

        // ---- D: h-side MFMA (kc 16..47), swapped operands ----
#pragma unroll
        for (int kk = 4; kk < 12; ++kk) {
            short8 a0 = *(const short8*)(hb + swzH(lrow, (4 * kk - 16 + 0) * 64 + kg * 16));
            short8 a1 = *(const short8*)(hb + swzH(lrow, (4 * kk - 16 + 1) * 64 + kg * 16));
            short8 a2 = *(const short8*)(hb + swzH(lrow, (4 * kk - 16 + 2) * 64 + kg * 16));
            short8 a3 = *(const short8*)(hb + swzH(lrow, (4 * kk - 16 + 3) * 64 + kg * 16));
            acc0 = __builtin_amdgcn_mfma_f32_16x16x32_bf16(Bf[4 * kk + 0], a0, acc0, 0, 0, 0);
            acc1 = __builtin_amdgcn_mfma_f32_16x16x32_bf16(Bf[4 * kk + 1], a1, acc1, 0, 0, 0);
            acc2 = __builtin_amdgcn_mfma_f32_16x16x32_bf16(Bf[4 * kk + 2], a2, acc2, 0, 0, 0);
            acc3 = __builtin_amdgcn_mfma_f32_16x16x32_bf16(Bf[4 * kk + 3], a3, acc3, 0, 0, 0);
        }

        // ---- E: epilogue. C^T: lane = batch row lrow, cols n0..n0+3 ----
        if (!has_next) {
            float4 o;
            o.x = fast_tanh(acc0[0] + acc1[0] + acc2[0] + acc3[0] + bias4.x);
            o.y = fast_tanh(acc0[1] + acc1[1] + acc2[1] + acc3[1] + bias4.y);
            o.z = fast_tanh(acc0[2] + acc1[2] + acc2[2] + acc3[2] + bias4.z);
            o.w = fast_tanh(acc0[3] + acc1[3] + acc2[3] + acc3[3] + bias4.w);
            *(float4*)(out + (size_t)(g * GROWS + lrow) * HDIM + n0) = o;
            break;
        }
        {
            unsigned short* hdst = hbuf + (size_t)((t + 1) & 1) * HBUF_ELEMS;
            float h0v = fast_tanh(acc0[0] + acc1[0] + acc2[0] + acc3[0] + bias4.x);
            float h1v = fast_tanh(acc0[1] + acc1[1] + acc2[1] + acc3[1] + bias4.y);
            float h2v = fast_tanh(acc0[2] + acc1[2] + acc2[2] + acc3[2] + bias4.z);
            float h3v = fast_tanh(acc0[3] + acc1[3] + acc2[3] + acc3[3] + bias4.w);
            unsigned int lo = (unsigned int)f2bf(h0v) | ((unsigned int)f2bf(h1v) << 16);
            unsigned int hi = (unsigned int)f2bf(h2v) | ((unsigned int)f2bf(h3v) << 16);
            st_u64_if(hdst + (size_t)(g * GROWS + lrow) * HDIM + n0, lo, hi);
        }

        // ---- F: drain stores (+x loads, long landed) then per-wave publish ----
        asm volatile("s_waitcnt vmcnt(0)" ::: "memory");
        __builtin_amdgcn_sched_barrier(0);
        if (lane == 0) st_u32_if(myflag, (unsigned int)(t + 1));

        // ---- G: stage x(t+1) regs -> xs[(t+1)&1] (no waits) ----
        {
            char* xnxt = xb + ((t + 1) & 1) * XBUFB;
#pragma unroll
            for (int q = 0; q < 4; ++q) {
                float4 a = xv[2 * q], b = xv[2 * q + 1];
                ushort8 w;
                w[0] = f2bf(a.x); w[1] = f2bf(a.y); w[2] = f2bf(a.z); w[3] = f2bf(a.w);
                w[4] = f2bf(b.x); w[5] = f2bf(b.y); w[6] = f2bf(b.z); w[7] = f2bf(b.w);
                *(ushort8*)(xnxt + swzX(sm, seg * 64 + q * 16)) = w;
            }
        }

        // ---- loop end: hs/xs reuse guard — all local waves past D-reads and
        // published (F) before anyone stages step t+1 (raw barrier, LDS wait) ----
        asm volatile("s_waitcnt lgkmcnt(0)" ::: "memory");
        __builtin_amdgcn_s_barrier();
        __builtin_amdgcn_sched_barrier(0);
    }
}

// ---------------------------------------------------------------------------
extern "C" void kernel_launch(void* const* d_in, const int* in_sizes, int n_in,
                              void* d_out, int out_size, void* d_ws, size_t ws_size,
                              hipStream_t stream) {
    const float* x  = (const float*)d_in[0];
    const float* h0 = (const float*)d_in[1];
    const float* Wx = (const float*)d_in[2];
    const float* bx = (const float*)d_in[3];
    const float* Wh = (const float*)d_in[4];
    const float* bh = (const float*)d_in[5];
    float* out = (float*)d_out;

    // workspace layout (128B-aligned pieces)
    const size_t OFF_WT = 0;                    // 1024*1536 bf16 = 3,145,728 B
    const size_t OFF_BS = 3145728;              // 1024 f32 = 4096 B
    const size_t OFF_HB = 3149824;              // 2*128*1024 bf16 = 524,288 B
    const size_t OFF_FL = 3674112;              // 512 u32 packed flags = 2048 B
    const size_t WS_NEED = 3676160;
    if (ws_size < WS_NEED) {                    // diagnostic: absmax ~1e6 => ws too small
        hipLaunchKernelGGL(ws_fail_kernel, dim3(1), dim3(1), 0, stream, out);
        return;
    }

    unsigned short* WT    = (unsigned short*)((char*)d_ws + OFF_WT);
    float*          bsum  = (float*)((char*)d_ws + OFF_BS);
    unsigned short* hbuf  = (unsigned short*)((char*)d_ws + OFF_HB);
    unsigned int*   flags = (unsigned int*)((char*)d_ws + OFF_FL);

    prep_transpose<<<dim3(IDIM / 32, HDIM / 32), dim3(32, 8), 0, stream>>>(Wx, WT, 0);
    prep_transpose<<<dim3(HDIM / 32, HDIM / 32), dim3(32, 8), 0, stream>>>(Wh, WT, IDIM);
    const int misc_total = HBUF_ELEMS + HDIM + NFLAG;
    prep_misc<<<dim3((misc_total + 255) / 256), dim3(256), 0, stream>>>(
        h0, bx, bh, bsum, hbuf, flags);
    rnn_fused<<<dim3(NGROUP * NCB), dim3(256), 0, stream>>>(
        x, WT, bsum, hbuf, flags, out);
}